// Round 1
// baseline (415.803 us; speedup 1.0000x reference)
//
#include <hip/hip_runtime.h>
#include <math.h>

// ---- problem constants (B=1, L=256, C=128, H=4, D=32) ----
// workspace layout (float offsets):
//   q_t : [256 r][4 h][256 pos][32 d]  = 8388608
//   k_t : same                          = 8388608
//   v_t : same                          = 8388608
//   bias: [4 h][256 j][256 i]           = 262144   (masked entries = 1e30 sentinel)
//   gate: [65536 tok][128]              = 8388608
#define Q_OFF 0u
#define K_OFF 8388608u
#define V_OFF 16777216u
#define B_OFF 25165824u
#define G_OFF 25427968u
// total floats = 33816576 -> 135.3 MB

// =====================================================================
// K1: fused LayerNorm + {qkv, pair(+mask sentinel), gate} projections.
// 1024 blocks x 256 threads; each block owns 64 consecutive tokens
// (all in one row i since 64 | 256).
// =====================================================================
__global__ __launch_bounds__(256) void k_ln_proj(
    const float* __restrict__ z, const float* __restrict__ gamma,
    const float* __restrict__ beta, const float* __restrict__ w_qkv,
    const float* __restrict__ w_pair, const float* __restrict__ w_gate,
    const float* __restrict__ b_gate, const int* __restrict__ src_mask,
    float* __restrict__ ws)
{
    __shared__ float zn_s[64 * 132];   // stride 132 floats: 16B-aligned rows, bank-spread
    const int tid = threadIdx.x;
    const int tb = blockIdx.x * 64;

    // ---- LayerNorm: 4 threads per token, 32 channels each ----
    {
        const int tl = tid >> 2, q4 = tid & 3;
        const float* zp = z + (size_t)(tb + tl) * 128 + q4 * 32;
        float zv[32];
        float s = 0.f, s2 = 0.f;
        #pragma unroll
        for (int k = 0; k < 8; ++k) {
            float4 v = ((const float4*)zp)[k];
            zv[k*4+0] = v.x; zv[k*4+1] = v.y; zv[k*4+2] = v.z; zv[k*4+3] = v.w;
            s  += v.x + v.y + v.z + v.w;
            s2 += v.x*v.x + v.y*v.y + v.z*v.z + v.w*v.w;
        }
        s  += __shfl_xor(s, 1);  s  += __shfl_xor(s, 2);
        s2 += __shfl_xor(s2, 1); s2 += __shfl_xor(s2, 2);
        const float mu  = s * (1.f/128.f);
        const float var = s2 * (1.f/128.f) - mu * mu;
        const float inv = rsqrtf(var + 1e-5f);
        #pragma unroll
        for (int k = 0; k < 32; ++k) {
            const int c = q4*32 + k;
            zn_s[tl*132 + c] = (zv[k] - mu) * inv * gamma[c] + beta[c];
        }
    }
    __syncthreads();

    const int ty = tid >> 5, tx = tid & 31;   // 8 token-groups x 32 output lanes

    // ---- qkv projection: 3 chunks of 128 outputs (q,k,v) ----
    for (int chunk = 0; chunk < 3; ++chunk) {
        float acc[8][4];
        #pragma unroll
        for (int a = 0; a < 8; ++a)
            #pragma unroll
            for (int m = 0; m < 4; ++m) acc[a][m] = 0.f;
        const float* W = w_qkv + chunk*128 + tx;
        for (int c = 0; c < 128; c += 4) {
            float4 a4[8];
            #pragma unroll
            for (int tm = 0; tm < 8; ++tm)
                a4[tm] = *(const float4*)&zn_s[(ty*8+tm)*132 + c];
            #pragma unroll
            for (int cc = 0; cc < 4; ++cc) {
                const float w0 = W[(c+cc)*384];
                const float w1 = W[(c+cc)*384 + 32];
                const float w2 = W[(c+cc)*384 + 64];
                const float w3 = W[(c+cc)*384 + 96];
                #pragma unroll
                for (int tm = 0; tm < 8; ++tm) {
                    const float a = ((const float*)&a4[tm])[cc];
                    acc[tm][0] = fmaf(a, w0, acc[tm][0]);
                    acc[tm][1] = fmaf(a, w1, acc[tm][1]);
                    acc[tm][2] = fmaf(a, w2, acc[tm][2]);
                    acc[tm][3] = fmaf(a, w3, acc[tm][3]);
                }
            }
        }
        // outputs: o = chunk*128 + tx + 32*m  ->  h = m, d = tx
        float* dst = ws + (chunk == 0 ? Q_OFF : (chunk == 1 ? K_OFF : V_OFF));
        #pragma unroll
        for (int tm = 0; tm < 8; ++tm) {
            const int t = tb + ty*8 + tm;
            const int i = t >> 8, j = t & 255;
            #pragma unroll
            for (int m = 0; m < 4; ++m)
                dst[(size_t)((i*4 + m)*256 + j)*32 + tx] = acc[tm][m];
        }
    }

    // ---- gate projection (128 outputs) ----
    {
        float acc[8][4];
        #pragma unroll
        for (int a = 0; a < 8; ++a)
            #pragma unroll
            for (int m = 0; m < 4; ++m) acc[a][m] = 0.f;
        const float* W = w_gate + tx;
        for (int c = 0; c < 128; c += 4) {
            float4 a4[8];
            #pragma unroll
            for (int tm = 0; tm < 8; ++tm)
                a4[tm] = *(const float4*)&zn_s[(ty*8+tm)*132 + c];
            #pragma unroll
            for (int cc = 0; cc < 4; ++cc) {
                const float w0 = W[(c+cc)*128];
                const float w1 = W[(c+cc)*128 + 32];
                const float w2 = W[(c+cc)*128 + 64];
                const float w3 = W[(c+cc)*128 + 96];
                #pragma unroll
                for (int tm = 0; tm < 8; ++tm) {
                    const float a = ((const float*)&a4[tm])[cc];
                    acc[tm][0] = fmaf(a, w0, acc[tm][0]);
                    acc[tm][1] = fmaf(a, w1, acc[tm][1]);
                    acc[tm][2] = fmaf(a, w2, acc[tm][2]);
                    acc[tm][3] = fmaf(a, w3, acc[tm][3]);
                }
            }
        }
        const float bg0 = b_gate[tx], bg1 = b_gate[tx+32],
                    bg2 = b_gate[tx+64], bg3 = b_gate[tx+96];
        #pragma unroll
        for (int tm = 0; tm < 8; ++tm) {
            const int t = tb + ty*8 + tm;
            float* gp = ws + G_OFF + (size_t)t * 128 + tx;
            gp[0]  = 1.f / (1.f + __expf(-(acc[tm][0] + bg0)));
            gp[32] = 1.f / (1.f + __expf(-(acc[tm][1] + bg1)));
            gp[64] = 1.f / (1.f + __expf(-(acc[tm][2] + bg2)));
            gp[96] = 1.f / (1.f + __expf(-(acc[tm][3] + bg3)));
        }
    }

    // ---- pair bias (4 outputs/token) + mask sentinel ----
    {
        const int tl = tid >> 2, h = tid & 3;
        float acc = 0.f;
        for (int c = 0; c < 128; c += 4) {
            float4 a4 = *(const float4*)&zn_s[tl*132 + c];
            acc = fmaf(a4.x, w_pair[(c+0)*4 + h], acc);
            acc = fmaf(a4.y, w_pair[(c+1)*4 + h], acc);
            acc = fmaf(a4.z, w_pair[(c+2)*4 + h], acc);
            acc = fmaf(a4.w, w_pair[(c+3)*4 + h], acc);
        }
        const int t = tb + tl;
        const int i = t >> 8, j = t & 255;
        // attn_mask = m_i*m_j with m = (mask==0 ? -1 : 1); masked iff product == -1
        const bool masked = (src_mask[i] == 0) != (src_mask[j] == 0);
        ws[B_OFF + (size_t)(h*256 + j)*256 + i] = masked ? 1e30f : acc;
    }
}

// =====================================================================
// K2: attention. Block per (row r, head h); thread i = query position.
// Online softmax over j, K/V staged in LDS. Writes pre-gate output to
// d_out (reused as scratch; K3 overwrites it).
// =====================================================================
__global__ __launch_bounds__(256) void k_attn(
    const float* __restrict__ ws, float* __restrict__ out)
{
    __shared__ float k_s[256 * 32];
    __shared__ float v_s[256 * 32];
    const int tid = threadIdx.x;
    const int rh = blockIdx.x;        // r*4 + h
    const int h  = rh & 3;

    const float4* kq = (const float4*)(ws + K_OFF + (size_t)rh * 8192);
    const float4* vq = (const float4*)(ws + V_OFF + (size_t)rh * 8192);
    for (int x = tid; x < 2048; x += 256) {
        ((float4*)k_s)[x] = kq[x];
        ((float4*)v_s)[x] = vq[x];
    }

    float q[32];
    {
        const float4* qq = (const float4*)(ws + Q_OFF + (size_t)rh * 8192 + tid * 32);
        #pragma unroll
        for (int k = 0; k < 8; ++k) {
            float4 v = qq[k];
            q[k*4+0] = v.x; q[k*4+1] = v.y; q[k*4+2] = v.z; q[k*4+3] = v.w;
        }
    }
    const float* bp = ws + B_OFF + (size_t)h * 65536 + tid;  // + j*256
    __syncthreads();

    const float inv_scale = 0.17677669529663687f;  // 1/sqrt(32)
    float m = -INFINITY, l = 0.f;
    float acc[32];
    #pragma unroll
    for (int d = 0; d < 32; ++d) acc[d] = 0.f;

    for (int j = 0; j < 256; ++j) {
        float dot = 0.f;
        #pragma unroll
        for (int d = 0; d < 32; d += 4) {
            float4 kk = *(const float4*)&k_s[j*32 + d];
            dot = fmaf(q[d+0], kk.x, dot);
            dot = fmaf(q[d+1], kk.y, dot);
            dot = fmaf(q[d+2], kk.z, dot);
            dot = fmaf(q[d+3], kk.w, dot);
        }
        const float b = bp[(size_t)j * 256];
        // sentinel 1e30 => masked => logit = -1e-9 (exact ref semantics)
        const float logit = (b > 1e29f) ? -1e-9f : fmaf(dot, inv_scale, b);
        if (logit > m) {                 // rare rescale
            const float corr = __expf(m - logit);
            l *= corr;
            #pragma unroll
            for (int d = 0; d < 32; ++d) acc[d] *= corr;
            m = logit;
        }
        const float p = __expf(logit - m);
        l += p;
        #pragma unroll
        for (int d = 0; d < 32; d += 4) {
            float4 vv = *(const float4*)&v_s[j*32 + d];
            acc[d+0] = fmaf(p, vv.x, acc[d+0]);
            acc[d+1] = fmaf(p, vv.y, acc[d+1]);
            acc[d+2] = fmaf(p, vv.z, acc[d+2]);
            acc[d+3] = fmaf(p, vv.w, acc[d+3]);
        }
    }
    const float invl = 1.f / l;
    float* op = out + ((size_t)(rh >> 2) * 256 + tid) * 128 + h * 32;
    #pragma unroll
    for (int d = 0; d < 32; d += 4) {
        float4 o;
        o.x = acc[d+0]*invl; o.y = acc[d+1]*invl;
        o.z = acc[d+2]*invl; o.w = acc[d+3]*invl;
        *(float4*)&op[d] = o;
    }
}

// =====================================================================
// K3: out = (gate * out_pre) @ w_out + b_out.  64-token tiles.
// Reads its own tokens (gate from ws, out_pre from d_out) into LDS,
// then overwrites d_out — no inter-block hazard.
// =====================================================================
__global__ __launch_bounds__(256) void k_out_proj(
    const float* __restrict__ ws, const float* __restrict__ w_out,
    const float* __restrict__ b_out, float* __restrict__ out)
{
    __shared__ float ga_s[64 * 132];
    const int tid = threadIdx.x;
    const int tb = blockIdx.x * 64;

    const float4* g4 = (const float4*)(ws + G_OFF) + (size_t)tb * 32;
    const float4* o4 = (const float4*)out + (size_t)tb * 32;
    for (int x = tid; x < 2048; x += 256) {
        float4 g = g4[x], o = o4[x];
        float4 r; r.x = g.x*o.x; r.y = g.y*o.y; r.z = g.z*o.z; r.w = g.w*o.w;
        *(float4*)&ga_s[(x >> 5)*132 + (x & 31)*4] = r;
    }
    __syncthreads();

    const int ty = tid >> 5, tx = tid & 31;
    float acc[8][4];
    #pragma unroll
    for (int a = 0; a < 8; ++a)
        #pragma unroll
        for (int m = 0; m < 4; ++m) acc[a][m] = 0.f;
    const float* W = w_out + tx;
    for (int c = 0; c < 128; c += 4) {
        float4 a4[8];
        #pragma unroll
        for (int tm = 0; tm < 8; ++tm)
            a4[tm] = *(const float4*)&ga_s[(ty*8+tm)*132 + c];
        #pragma unroll
        for (int cc = 0; cc < 4; ++cc) {
            const float w0 = W[(c+cc)*128];
            const float w1 = W[(c+cc)*128 + 32];
            const float w2 = W[(c+cc)*128 + 64];
            const float w3 = W[(c+cc)*128 + 96];
            #pragma unroll
            for (int tm = 0; tm < 8; ++tm) {
                const float a = ((const float*)&a4[tm])[cc];
                acc[tm][0] = fmaf(a, w0, acc[tm][0]);
                acc[tm][1] = fmaf(a, w1, acc[tm][1]);
                acc[tm][2] = fmaf(a, w2, acc[tm][2]);
                acc[tm][3] = fmaf(a, w3, acc[tm][3]);
            }
        }
    }
    const float bo0 = b_out[tx], bo1 = b_out[tx+32],
                bo2 = b_out[tx+64], bo3 = b_out[tx+96];
    #pragma unroll
    for (int tm = 0; tm < 8; ++tm) {
        const int t = tb + ty*8 + tm;
        float* op = out + (size_t)t * 128 + tx;
        op[0]  = acc[tm][0] + bo0;
        op[32] = acc[tm][1] + bo1;
        op[64] = acc[tm][2] + bo2;
        op[96] = acc[tm][3] + bo3;
    }
}

extern "C" void kernel_launch(void* const* d_in, const int* in_sizes, int n_in,
                              void* d_out, int out_size, void* d_ws, size_t ws_size,
                              hipStream_t stream)
{
    const float* z       = (const float*)d_in[0];
    const float* gamma   = (const float*)d_in[1];
    const float* beta    = (const float*)d_in[2];
    const float* w_qkv   = (const float*)d_in[3];
    const float* w_pair  = (const float*)d_in[4];
    const float* w_gate  = (const float*)d_in[5];
    const float* b_gate  = (const float*)d_in[6];
    const float* w_out   = (const float*)d_in[7];
    const float* b_out   = (const float*)d_in[8];
    const int*   src_mask= (const int*)d_in[9];
    float* out = (float*)d_out;
    float* ws  = (float*)d_ws;

    hipLaunchKernelGGL(k_ln_proj, dim3(1024), dim3(256), 0, stream,
                       z, gamma, beta, w_qkv, w_pair, w_gate, b_gate, src_mask, ws);
    hipLaunchKernelGGL(k_attn, dim3(1024), dim3(256), 0, stream, ws, out);
    hipLaunchKernelGGL(k_out_proj, dim3(1024), dim3(256), 0, stream,
                       ws, w_out, b_out, out);
}

// Round 2
// 231.986 us; speedup vs baseline: 1.7924x; 1.7924x over previous
//
#include <hip/hip_runtime.h>
#include <hip/hip_bf16.h>
#include <math.h>

typedef __attribute__((ext_vector_type(4))) short short4v;
typedef __attribute__((ext_vector_type(8))) short short8v;
typedef __attribute__((ext_vector_type(4))) float f32x4;

// ---- problem constants (B=1, L=256, C=128, H=4, D=32) ----
// workspace layout (BYTE offsets):
//   qb  : bf16 [256r*4h][256 pos][32 d]   16 MB
//   kb  : bf16 same                        16 MB
//   vb  : bf16 same                        16 MB
//   bias: f32  [4 h][256 j][256 i]          1 MB  (masked entries = 1e30 sentinel)
//   gate: f32  [65536 tok][128]            33.5 MB
#define QB_OFF    0
#define KB_OFF    16777216
#define VB_OFF    33554432
#define BIAS_OFF  50331648
#define GATE_OFF  51380224

static __device__ __forceinline__ short f2bf(float x) {
    __hip_bfloat16 h = __float2bfloat16(x);
    return *reinterpret_cast<short*>(&h);
}

// =====================================================================
// K1: fused LayerNorm + {qkv(bf16), pair(+mask sentinel), gate} proj.
// 1024 blocks x 256 threads; each block owns 64 consecutive tokens.
// =====================================================================
__global__ __launch_bounds__(256) void k_ln_proj(
    const float* __restrict__ z, const float* __restrict__ gamma,
    const float* __restrict__ beta, const float* __restrict__ w_qkv,
    const float* __restrict__ w_pair, const float* __restrict__ w_gate,
    const float* __restrict__ b_gate, const int* __restrict__ src_mask,
    __hip_bfloat16* __restrict__ qb, __hip_bfloat16* __restrict__ kb,
    __hip_bfloat16* __restrict__ vb, float* __restrict__ biasf,
    float* __restrict__ gatef)
{
    __shared__ float zn_s[64 * 132];
    const int tid = threadIdx.x;
    const int tb = blockIdx.x * 64;

    // ---- LayerNorm: 4 threads per token ----
    {
        const int tl = tid >> 2, q4 = tid & 3;
        const float* zp = z + (size_t)(tb + tl) * 128 + q4 * 32;
        float zv[32];
        float s = 0.f, s2 = 0.f;
        #pragma unroll
        for (int k = 0; k < 8; ++k) {
            float4 v = ((const float4*)zp)[k];
            zv[k*4+0] = v.x; zv[k*4+1] = v.y; zv[k*4+2] = v.z; zv[k*4+3] = v.w;
            s  += v.x + v.y + v.z + v.w;
            s2 += v.x*v.x + v.y*v.y + v.z*v.z + v.w*v.w;
        }
        s  += __shfl_xor(s, 1);  s  += __shfl_xor(s, 2);
        s2 += __shfl_xor(s2, 1); s2 += __shfl_xor(s2, 2);
        const float mu  = s * (1.f/128.f);
        const float var = s2 * (1.f/128.f) - mu * mu;
        const float inv = rsqrtf(var + 1e-5f);
        #pragma unroll
        for (int k = 0; k < 32; ++k) {
            const int c = q4*32 + k;
            zn_s[tl*132 + c] = (zv[k] - mu) * inv * gamma[c] + beta[c];
        }
    }
    __syncthreads();

    const int ty = tid >> 5, tx = tid & 31;

    // ---- qkv projection (bf16 outputs) ----
    for (int chunk = 0; chunk < 3; ++chunk) {
        float acc[8][4];
        #pragma unroll
        for (int a = 0; a < 8; ++a)
            #pragma unroll
            for (int m = 0; m < 4; ++m) acc[a][m] = 0.f;
        const float* W = w_qkv + chunk*128 + tx;
        for (int c = 0; c < 128; c += 4) {
            float4 a4[8];
            #pragma unroll
            for (int tm = 0; tm < 8; ++tm)
                a4[tm] = *(const float4*)&zn_s[(ty*8+tm)*132 + c];
            #pragma unroll
            for (int cc = 0; cc < 4; ++cc) {
                const float w0 = W[(c+cc)*384];
                const float w1 = W[(c+cc)*384 + 32];
                const float w2 = W[(c+cc)*384 + 64];
                const float w3 = W[(c+cc)*384 + 96];
                #pragma unroll
                for (int tm = 0; tm < 8; ++tm) {
                    const float a = ((const float*)&a4[tm])[cc];
                    acc[tm][0] = fmaf(a, w0, acc[tm][0]);
                    acc[tm][1] = fmaf(a, w1, acc[tm][1]);
                    acc[tm][2] = fmaf(a, w2, acc[tm][2]);
                    acc[tm][3] = fmaf(a, w3, acc[tm][3]);
                }
            }
        }
        __hip_bfloat16* dst = (chunk == 0 ? qb : (chunk == 1 ? kb : vb));
        #pragma unroll
        for (int tm = 0; tm < 8; ++tm) {
            const int t = tb + ty*8 + tm;
            const int i = t >> 8, j = t & 255;
            #pragma unroll
            for (int m = 0; m < 4; ++m)
                dst[(size_t)((i*4 + m)*256 + j)*32 + tx] = __float2bfloat16(acc[tm][m]);
        }
    }

    // ---- gate projection ----
    {
        float acc[8][4];
        #pragma unroll
        for (int a = 0; a < 8; ++a)
            #pragma unroll
            for (int m = 0; m < 4; ++m) acc[a][m] = 0.f;
        const float* W = w_gate + tx;
        for (int c = 0; c < 128; c += 4) {
            float4 a4[8];
            #pragma unroll
            for (int tm = 0; tm < 8; ++tm)
                a4[tm] = *(const float4*)&zn_s[(ty*8+tm)*132 + c];
            #pragma unroll
            for (int cc = 0; cc < 4; ++cc) {
                const float w0 = W[(c+cc)*128];
                const float w1 = W[(c+cc)*128 + 32];
                const float w2 = W[(c+cc)*128 + 64];
                const float w3 = W[(c+cc)*128 + 96];
                #pragma unroll
                for (int tm = 0; tm < 8; ++tm) {
                    const float a = ((const float*)&a4[tm])[cc];
                    acc[tm][0] = fmaf(a, w0, acc[tm][0]);
                    acc[tm][1] = fmaf(a, w1, acc[tm][1]);
                    acc[tm][2] = fmaf(a, w2, acc[tm][2]);
                    acc[tm][3] = fmaf(a, w3, acc[tm][3]);
                }
            }
        }
        const float bg0 = b_gate[tx], bg1 = b_gate[tx+32],
                    bg2 = b_gate[tx+64], bg3 = b_gate[tx+96];
        #pragma unroll
        for (int tm = 0; tm < 8; ++tm) {
            const int t = tb + ty*8 + tm;
            float* gp = gatef + (size_t)t * 128 + tx;
            gp[0]  = 1.f / (1.f + __expf(-(acc[tm][0] + bg0)));
            gp[32] = 1.f / (1.f + __expf(-(acc[tm][1] + bg1)));
            gp[64] = 1.f / (1.f + __expf(-(acc[tm][2] + bg2)));
            gp[96] = 1.f / (1.f + __expf(-(acc[tm][3] + bg3)));
        }
    }

    // ---- pair bias + mask sentinel ----
    {
        const int tl = tid >> 2, h = tid & 3;
        float acc = 0.f;
        for (int c = 0; c < 128; c += 4) {
            float4 a4 = *(const float4*)&zn_s[tl*132 + c];
            acc = fmaf(a4.x, w_pair[(c+0)*4 + h], acc);
            acc = fmaf(a4.y, w_pair[(c+1)*4 + h], acc);
            acc = fmaf(a4.z, w_pair[(c+2)*4 + h], acc);
            acc = fmaf(a4.w, w_pair[(c+3)*4 + h], acc);
        }
        const int t = tb + tl;
        const int i = t >> 8, j = t & 255;
        const bool masked = (src_mask[i] == 0) != (src_mask[j] == 0);
        biasf[(size_t)(h*256 + j)*256 + i] = masked ? 1e30f : acc;
    }
}

// =====================================================================
// K2: MFMA attention. Block = (h, r): 128 threads = 2 waves; wave w owns
// i-tiles w*8..w*8+7. S^T = mfma16x16x32(K-frag, Q-frag) so each lane
// holds a softmax column lane-locally; P^T frag layout == A-operand of
// mfma_f32_16x16x16bf16_1k -> PV entirely in registers.
// LDS: K tile, 80B padded row stride (2-way bank alias = free).
// =====================================================================
__global__ __launch_bounds__(128, 2) void k_attn_mfma(
    const __hip_bfloat16* __restrict__ qb_, const __hip_bfloat16* __restrict__ kb_,
    const __hip_bfloat16* __restrict__ vb_, const float* __restrict__ biasf,
    float* __restrict__ out)
{
    __shared__ __align__(16) char klds[256 * 80];   // 20 KB
    const int tid  = threadIdx.x;
    const int lane = tid & 63;
    const int wv   = tid >> 6;
    const int h = blockIdx.x >> 8, r = blockIdx.x & 255;
    const int rh = r * 4 + h;
    const int l15 = lane & 15, lg4 = lane >> 4;

    const ushort* qg = (const ushort*)qb_ + (size_t)rh * 8192;
    const ushort* kg = (const ushort*)kb_ + (size_t)rh * 8192;
    const ushort* vg = (const ushort*)vb_ + (size_t)rh * 8192;

    // ---- V B-frags (16x16x16): lane holds V[jt*16+lg4*4+e][dt*16+l15] ----
    short4v vfrag[16][2];
    #pragma unroll
    for (int jt = 0; jt < 16; ++jt)
        #pragma unroll
        for (int dt = 0; dt < 2; ++dt) {
            short4v f;
            #pragma unroll
            for (int e = 0; e < 4; ++e)
                f[e] = (short)vg[(size_t)(jt*16 + lg4*4 + e)*32 + dt*16 + l15];
            vfrag[jt][dt] = f;
        }

    // ---- stage K into LDS (row stride 80 B) ----
    #pragma unroll
    for (int t = 0; t < 8; ++t) {
        uint4 kv = *(const uint4*)(kg + t*1024 + tid*8);
        *(uint4*)(klds + (t*32 + (tid >> 2))*80 + (tid & 3)*16) = kv;
    }
    __syncthreads();

    const float inv_scale = 0.17677669529663687f;  // 1/sqrt(32)

    for (int ii = 0; ii < 8; ++ii) {
        const int it = wv*8 + ii;
        // Q B-frag: lane holds Q[it*16+l15][lg4*8+e]
        short8v qf = *(const short8v*)(qg + (it*16 + l15)*32 + lg4*8);

        // S^T tiles: s[jt][e] = S[j = jt*16+lg4*4+e][i = it*16+l15]
        f32x4 s[16];
        #pragma unroll
        for (int jt = 0; jt < 16; ++jt) {
            short8v kf = *(const short8v*)(klds + (jt*16 + l15)*80 + lg4*16);
            s[jt] = __builtin_amdgcn_mfma_f32_16x16x32_bf16(
                        kf, qf, (f32x4){0.f,0.f,0.f,0.f}, 0, 0, 0);
        }

        // logits = dot/scale + bias, with exact -1e-9 mask semantics
        const float* bp = biasf + (size_t)h * 65536 + it*16 + l15;
        #pragma unroll
        for (int jt = 0; jt < 16; ++jt)
            #pragma unroll
            for (int e = 0; e < 4; ++e) {
                const float b = bp[(size_t)(jt*16 + lg4*4 + e) * 256];
                s[jt][e] = (b > 1e29f) ? -1e-9f : fmaf(s[jt][e], inv_scale, b);
            }

        // softmax over j: per-lane 64 values + combine 4 lane-groups
        float m = -INFINITY;
        #pragma unroll
        for (int jt = 0; jt < 16; ++jt) {
            const float a = fmaxf(fmaxf(s[jt][0], s[jt][1]),
                                  fmaxf(s[jt][2], s[jt][3]));
            m = fmaxf(m, a);
        }
        m = fmaxf(m, __shfl_xor(m, 16));
        m = fmaxf(m, __shfl_xor(m, 32));

        float lsum = 0.f;
        #pragma unroll
        for (int jt = 0; jt < 16; ++jt)
            #pragma unroll
            for (int e = 0; e < 4; ++e) {
                const float p = __expf(s[jt][e] - m);
                s[jt][e] = p;
                lsum += p;
            }
        lsum += __shfl_xor(lsum, 16);
        lsum += __shfl_xor(lsum, 32);

        // pack P -> bf16 A-frags (layout already matches 16x16x16 A operand)
        short4v pa[16];
        #pragma unroll
        for (int jt = 0; jt < 16; ++jt) {
            short4v t4;
            t4[0] = f2bf(s[jt][0]); t4[1] = f2bf(s[jt][1]);
            t4[2] = f2bf(s[jt][2]); t4[3] = f2bf(s[jt][3]);
            pa[jt] = t4;
        }

        // PV: out[i-tile 16][32 d] via 16x16x16 MFMAs, K=16 per jt
        f32x4 o0 = {0.f,0.f,0.f,0.f}, o1 = {0.f,0.f,0.f,0.f};
        #pragma unroll
        for (int jt = 0; jt < 16; ++jt) {
            o0 = __builtin_amdgcn_mfma_f32_16x16x16bf16_1k(pa[jt], vfrag[jt][0], o0, 0, 0, 0);
            o1 = __builtin_amdgcn_mfma_f32_16x16x16bf16_1k(pa[jt], vfrag[jt][1], o1, 0, 0, 0);
        }

        // per-output-row 1/l (row i = lg4*4+e lives at lane i in group 0)
        const float invl = 1.f / lsum;
        float il[4];
        #pragma unroll
        for (int e = 0; e < 4; ++e) il[e] = __shfl(invl, lg4*4 + e);

        // store: D row = i_local = lg4*4+e, col = d_local = l15
        float* op = out + ((size_t)(r*256 + it*16) * 128) + h*32;
        #pragma unroll
        for (int e = 0; e < 4; ++e) {
            op[(lg4*4 + e)*128 +      l15] = o0[e] * il[e];
            op[(lg4*4 + e)*128 + 16 + l15] = o1[e] * il[e];
        }
    }
}

// =====================================================================
// K3: out = (gate * out_pre) @ w_out + b_out.  64-token tiles.
// =====================================================================
__global__ __launch_bounds__(256) void k_out_proj(
    const float* __restrict__ gatef, const float* __restrict__ w_out,
    const float* __restrict__ b_out, float* __restrict__ out)
{
    __shared__ float ga_s[64 * 132];
    const int tid = threadIdx.x;
    const int tb = blockIdx.x * 64;

    const float4* g4 = (const float4*)gatef + (size_t)tb * 32;
    const float4* o4 = (const float4*)out + (size_t)tb * 32;
    for (int x = tid; x < 2048; x += 256) {
        float4 g = g4[x], o = o4[x];
        float4 r; r.x = g.x*o.x; r.y = g.y*o.y; r.z = g.z*o.z; r.w = g.w*o.w;
        *(float4*)&ga_s[(x >> 5)*132 + (x & 31)*4] = r;
    }
    __syncthreads();

    const int ty = tid >> 5, tx = tid & 31;
    float acc[8][4];
    #pragma unroll
    for (int a = 0; a < 8; ++a)
        #pragma unroll
        for (int m = 0; m < 4; ++m) acc[a][m] = 0.f;
    const float* W = w_out + tx;
    for (int c = 0; c < 128; c += 4) {
        float4 a4[8];
        #pragma unroll
        for (int tm = 0; tm < 8; ++tm)
            a4[tm] = *(const float4*)&ga_s[(ty*8+tm)*132 + c];
        #pragma unroll
        for (int cc = 0; cc < 4; ++cc) {
            const float w0 = W[(c+cc)*128];
            const float w1 = W[(c+cc)*128 + 32];
            const float w2 = W[(c+cc)*128 + 64];
            const float w3 = W[(c+cc)*128 + 96];
            #pragma unroll
            for (int tm = 0; tm < 8; ++tm) {
                const float a = ((const float*)&a4[tm])[cc];
                acc[tm][0] = fmaf(a, w0, acc[tm][0]);
                acc[tm][1] = fmaf(a, w1, acc[tm][1]);
                acc[tm][2] = fmaf(a, w2, acc[tm][2]);
                acc[tm][3] = fmaf(a, w3, acc[tm][3]);
            }
        }
    }
    const float bo0 = b_out[tx], bo1 = b_out[tx+32],
                bo2 = b_out[tx+64], bo3 = b_out[tx+96];
    #pragma unroll
    for (int tm = 0; tm < 8; ++tm) {
        const int t = tb + ty*8 + tm;
        float* op = out + (size_t)t * 128 + tx;
        op[0]  = acc[tm][0] + bo0;
        op[32] = acc[tm][1] + bo1;
        op[64] = acc[tm][2] + bo2;
        op[96] = acc[tm][3] + bo3;
    }
}

extern "C" void kernel_launch(void* const* d_in, const int* in_sizes, int n_in,
                              void* d_out, int out_size, void* d_ws, size_t ws_size,
                              hipStream_t stream)
{
    const float* z       = (const float*)d_in[0];
    const float* gamma   = (const float*)d_in[1];
    const float* beta    = (const float*)d_in[2];
    const float* w_qkv   = (const float*)d_in[3];
    const float* w_pair  = (const float*)d_in[4];
    const float* w_gate  = (const float*)d_in[5];
    const float* b_gate  = (const float*)d_in[6];
    const float* w_out   = (const float*)d_in[7];
    const float* b_out   = (const float*)d_in[8];
    const int*   src_mask= (const int*)d_in[9];
    float* out = (float*)d_out;
    char*  wsb = (char*)d_ws;

    __hip_bfloat16* qb = (__hip_bfloat16*)(wsb + QB_OFF);
    __hip_bfloat16* kb = (__hip_bfloat16*)(wsb + KB_OFF);
    __hip_bfloat16* vb = (__hip_bfloat16*)(wsb + VB_OFF);
    float* biasf = (float*)(wsb + BIAS_OFF);
    float* gatef = (float*)(wsb + GATE_OFF);

    hipLaunchKernelGGL(k_ln_proj, dim3(1024), dim3(256), 0, stream,
                       z, gamma, beta, w_qkv, w_pair, w_gate, b_gate, src_mask,
                       qb, kb, vb, biasf, gatef);
    hipLaunchKernelGGL(k_attn_mfma, dim3(1024), dim3(128), 0, stream,
                       qb, kb, vb, biasf, out);
    hipLaunchKernelGGL(k_out_proj, dim3(1024), dim3(256), 0, stream,
                       gatef, w_out, b_out, out);
}

// Round 3
// 112.306 us; speedup vs baseline: 3.7024x; 2.0657x over previous
//
#include <hip/hip_runtime.h>
#include <hip/hip_bf16.h>
#include <math.h>

typedef __attribute__((ext_vector_type(4))) short short4v;
typedef __attribute__((ext_vector_type(8))) short short8v;
typedef __attribute__((ext_vector_type(4))) float f32x4;

// ---- problem constants (B=1, L=256, C=128, H=4, D=32) ----
// workspace layout (BYTE offsets):
//   qb   : bf16 [256r*4h][256 pos][32 d]   16 MB
//   kb   : bf16 same                        16 MB
//   vb   : bf16 same                        16 MB
//   bias : f32  [4 h][256 j][256 i]          1 MB (masked = 1e30 sentinel)
//   gateb: bf16 [65536 tok][128]            16 MB
//   attb : bf16 [65536 tok][128]            16 MB
//   wT   : bf16 [512 n][128 k]             128 KB (qkv cols 0-383, gate 384-511)
//   woT  : bf16 [128 n][128 k]              32 KB
#define QB_OFF    0
#define KB_OFF    16777216
#define VB_OFF    33554432
#define BIAS_OFF  50331648
#define GATEB_OFF 51380224
#define ATTB_OFF  68157440
#define WT_OFF    84934656
#define WOT_OFF   85065728

static __device__ __forceinline__ short f2bf(float x) {
    __hip_bfloat16 h = __float2bfloat16(x);
    return *reinterpret_cast<short*>(&h);
}
static __device__ __forceinline__ float bf2f(short x) {
    __hip_bfloat16 h = *reinterpret_cast<__hip_bfloat16*>(&x);
    return __bfloat162float(h);
}

// =====================================================================
// K0: transpose+convert weights to bf16 [n][k] layout (run once/launch).
// grid 640 x 128 threads. n<384: w_qkv, n<512: w_gate, else w_out.
// =====================================================================
__global__ __launch_bounds__(128) void k_prep_w(
    const float* __restrict__ w_qkv, const float* __restrict__ w_gate,
    const float* __restrict__ w_out, __hip_bfloat16* __restrict__ wT,
    __hip_bfloat16* __restrict__ woT)
{
    const int n = blockIdx.x, k = threadIdx.x;
    if (n < 384)      wT[n*128 + k]        = __float2bfloat16(w_qkv[k*384 + n]);
    else if (n < 512) wT[n*128 + k]        = __float2bfloat16(w_gate[k*128 + (n-384)]);
    else              woT[(n-512)*128 + k] = __float2bfloat16(w_out[k*128 + (n-512)]);
}

// =====================================================================
// K1: LN (registers, A-frag layout) + pair bias (f32) + MFMA projections.
// 512 blocks x 256 thr (4 waves); wave owns 32 tokens.
// Lane (l15,lg4) holds channels {ks*32+lg4*8+e} of tokens {mt*16+l15}.
// B-frags read directly from global bf16 wT (L2-resident, no LDS).
// =====================================================================
__global__ __launch_bounds__(256) void k1_ln_proj(
    const float* __restrict__ z, const float* __restrict__ gamma,
    const float* __restrict__ beta, const float* __restrict__ w_pair,
    const float* __restrict__ b_gate, const int* __restrict__ src_mask,
    const __hip_bfloat16* __restrict__ wT,
    __hip_bfloat16* __restrict__ qb, __hip_bfloat16* __restrict__ kb,
    __hip_bfloat16* __restrict__ vb, float* __restrict__ biasf,
    __hip_bfloat16* __restrict__ gateb)
{
    const int tid = threadIdx.x;
    const int lane = tid & 63, wv = tid >> 6;
    const int l15 = lane & 15, lg4 = lane >> 4;
    const int tokbase = blockIdx.x * 128 + wv * 32;

    // ---- load z, compute moments ----
    float zn[2][32];
    float s[2] = {0.f, 0.f}, s2[2] = {0.f, 0.f};
    #pragma unroll
    for (int mt = 0; mt < 2; ++mt) {
        const float* zp = z + (size_t)(tokbase + mt*16 + l15) * 128 + lg4*8;
        #pragma unroll
        for (int ks = 0; ks < 4; ++ks) {
            float4 a = *(const float4*)(zp + ks*32);
            float4 b = *(const float4*)(zp + ks*32 + 4);
            zn[mt][ks*8+0] = a.x; zn[mt][ks*8+1] = a.y;
            zn[mt][ks*8+2] = a.z; zn[mt][ks*8+3] = a.w;
            zn[mt][ks*8+4] = b.x; zn[mt][ks*8+5] = b.y;
            zn[mt][ks*8+6] = b.z; zn[mt][ks*8+7] = b.w;
            s[mt]  += a.x + a.y + a.z + a.w + b.x + b.y + b.z + b.w;
            s2[mt] += a.x*a.x + a.y*a.y + a.z*a.z + a.w*a.w
                    + b.x*b.x + b.y*b.y + b.z*b.z + b.w*b.w;
        }
    }
    #pragma unroll
    for (int mt = 0; mt < 2; ++mt) {
        s[mt]  += __shfl_xor(s[mt], 16);  s[mt]  += __shfl_xor(s[mt], 32);
        s2[mt] += __shfl_xor(s2[mt], 16); s2[mt] += __shfl_xor(s2[mt], 32);
    }

    // ---- normalize (gamma/beta shared across mt) ----
    #pragma unroll
    for (int ks = 0; ks < 4; ++ks) {
        float4 g0 = *(const float4*)(gamma + ks*32 + lg4*8);
        float4 g1 = *(const float4*)(gamma + ks*32 + lg4*8 + 4);
        float4 b0 = *(const float4*)(beta  + ks*32 + lg4*8);
        float4 b1 = *(const float4*)(beta  + ks*32 + lg4*8 + 4);
        float gg[8] = {g0.x,g0.y,g0.z,g0.w,g1.x,g1.y,g1.z,g1.w};
        float bb[8] = {b0.x,b0.y,b0.z,b0.w,b1.x,b1.y,b1.z,b1.w};
        #pragma unroll
        for (int mt = 0; mt < 2; ++mt) {
            const float mu  = s[mt] * (1.f/128.f);
            const float inv = rsqrtf(s2[mt]*(1.f/128.f) - mu*mu + 1e-5f);
            #pragma unroll
            for (int e = 0; e < 8; ++e)
                zn[mt][ks*8+e] = (zn[mt][ks*8+e] - mu) * inv * gg[e] + bb[e];
        }
    }

    // ---- pair bias from f32 zn + mask sentinel ----
    {
        float pr[2][4] = {{0,0,0,0},{0,0,0,0}};
        #pragma unroll
        for (int ks = 0; ks < 4; ++ks)
            #pragma unroll
            for (int e = 0; e < 8; ++e) {
                float4 wp = *(const float4*)(w_pair + (ks*32 + lg4*8 + e)*4);
                #pragma unroll
                for (int mt = 0; mt < 2; ++mt) {
                    const float a = zn[mt][ks*8+e];
                    pr[mt][0] = fmaf(a, wp.x, pr[mt][0]);
                    pr[mt][1] = fmaf(a, wp.y, pr[mt][1]);
                    pr[mt][2] = fmaf(a, wp.z, pr[mt][2]);
                    pr[mt][3] = fmaf(a, wp.w, pr[mt][3]);
                }
            }
        #pragma unroll
        for (int mt = 0; mt < 2; ++mt)
            #pragma unroll
            for (int h = 0; h < 4; ++h) {
                pr[mt][h] += __shfl_xor(pr[mt][h], 16);
                pr[mt][h] += __shfl_xor(pr[mt][h], 32);
            }
        if (lg4 == 0) {
            #pragma unroll
            for (int mt = 0; mt < 2; ++mt) {
                const int t = tokbase + mt*16 + l15;
                const int i = t >> 8, j = t & 255;
                const bool masked = (src_mask[i] == 0) != (src_mask[j] == 0);
                #pragma unroll
                for (int h = 0; h < 4; ++h)
                    biasf[(size_t)(h*256 + j)*256 + i] = masked ? 1e30f : pr[mt][h];
            }
        }
    }

    // ---- pack A-frags ----
    short8v afr[2][4];
    #pragma unroll
    for (int mt = 0; mt < 2; ++mt)
        #pragma unroll
        for (int ks = 0; ks < 4; ++ks) {
            short8v f;
            #pragma unroll
            for (int e = 0; e < 8; ++e) f[e] = f2bf(zn[mt][ks*8+e]);
            afr[mt][ks] = f;
        }

    // ---- GEMM over 8 chunks of 64 cols (0-5: qkv, 6-7: gate) ----
    const ushort* wTu = (const ushort*)wT;
    for (int ch = 0; ch < 8; ++ch) {
        f32x4 acc[2][4];
        #pragma unroll
        for (int mt = 0; mt < 2; ++mt)
            #pragma unroll
            for (int nt = 0; nt < 4; ++nt) acc[mt][nt] = (f32x4){0.f,0.f,0.f,0.f};
        const ushort* Bb = wTu + (size_t)ch * 64 * 128;
        #pragma unroll
        for (int ks = 0; ks < 4; ++ks)
            #pragma unroll
            for (int nt = 0; nt < 4; ++nt) {
                short8v bfr = *(const short8v*)(Bb + (nt*16 + l15)*128 + ks*32 + lg4*8);
                acc[0][nt] = __builtin_amdgcn_mfma_f32_16x16x32_bf16(afr[0][ks], bfr, acc[0][nt], 0,0,0);
                acc[1][nt] = __builtin_amdgcn_mfma_f32_16x16x32_bf16(afr[1][ks], bfr, acc[1][nt], 0,0,0);
            }
        if (ch < 6) {
            __hip_bfloat16* dst = (ch < 2 ? qb : (ch < 4 ? kb : vb));
            #pragma unroll
            for (int mt = 0; mt < 2; ++mt)
                #pragma unroll
                for (int nt = 0; nt < 4; ++nt) {
                    const int nh = (ch & 1)*64 + nt*16 + l15;   // col within q/k/v
                    const int h = nh >> 5, d = nh & 31;
                    #pragma unroll
                    for (int e = 0; e < 4; ++e) {
                        const int t = tokbase + mt*16 + lg4*4 + e;
                        const int i = t >> 8, j = t & 255;
                        dst[(size_t)((i*4 + h)*256 + j)*32 + d] = __float2bfloat16(acc[mt][nt][e]);
                    }
                }
        } else {
            #pragma unroll
            for (int mt = 0; mt < 2; ++mt)
                #pragma unroll
                for (int nt = 0; nt < 4; ++nt) {
                    const int c = (ch - 6)*64 + nt*16 + l15;
                    const float bg = b_gate[c];
                    #pragma unroll
                    for (int e = 0; e < 4; ++e) {
                        const int t = tokbase + mt*16 + lg4*4 + e;
                        const float v = 1.f / (1.f + __expf(-(acc[mt][nt][e] + bg)));
                        gateb[(size_t)t*128 + c] = __float2bfloat16(v);
                    }
                }
        }
    }
}

// =====================================================================
// K2: MFMA attention (unchanged structure), now writes bf16 to attb.
// =====================================================================
__global__ __launch_bounds__(128, 2) void k_attn_mfma(
    const __hip_bfloat16* __restrict__ qb_, const __hip_bfloat16* __restrict__ kb_,
    const __hip_bfloat16* __restrict__ vb_, const float* __restrict__ biasf,
    __hip_bfloat16* __restrict__ attb)
{
    __shared__ __align__(16) char klds[256 * 80];   // 20 KB
    const int tid  = threadIdx.x;
    const int lane = tid & 63;
    const int wv   = tid >> 6;
    const int h = blockIdx.x >> 8, r = blockIdx.x & 255;
    const int rh = r * 4 + h;
    const int l15 = lane & 15, lg4 = lane >> 4;

    const ushort* qg = (const ushort*)qb_ + (size_t)rh * 8192;
    const ushort* kg = (const ushort*)kb_ + (size_t)rh * 8192;
    const ushort* vg = (const ushort*)vb_ + (size_t)rh * 8192;

    // V B-frags (16x16x16): lane holds V[jt*16+lg4*4+e][dt*16+l15]
    short4v vfrag[16][2];
    #pragma unroll
    for (int jt = 0; jt < 16; ++jt)
        #pragma unroll
        for (int dt = 0; dt < 2; ++dt) {
            short4v f;
            #pragma unroll
            for (int e = 0; e < 4; ++e)
                f[e] = (short)vg[(size_t)(jt*16 + lg4*4 + e)*32 + dt*16 + l15];
            vfrag[jt][dt] = f;
        }

    // stage K into LDS (row stride 80 B)
    #pragma unroll
    for (int t = 0; t < 8; ++t) {
        uint4 kv = *(const uint4*)(kg + t*1024 + tid*8);
        *(uint4*)(klds + (t*32 + (tid >> 2))*80 + (tid & 3)*16) = kv;
    }
    __syncthreads();

    const float inv_scale = 0.17677669529663687f;  // 1/sqrt(32)

    for (int ii = 0; ii < 8; ++ii) {
        const int it = wv*8 + ii;
        short8v qf = *(const short8v*)(qg + (it*16 + l15)*32 + lg4*8);

        f32x4 s[16];
        #pragma unroll
        for (int jt = 0; jt < 16; ++jt) {
            short8v kf = *(const short8v*)(klds + (jt*16 + l15)*80 + lg4*16);
            s[jt] = __builtin_amdgcn_mfma_f32_16x16x32_bf16(
                        kf, qf, (f32x4){0.f,0.f,0.f,0.f}, 0, 0, 0);
        }

        const float* bp = biasf + (size_t)h * 65536 + it*16 + l15;
        #pragma unroll
        for (int jt = 0; jt < 16; ++jt)
            #pragma unroll
            for (int e = 0; e < 4; ++e) {
                const float b = bp[(size_t)(jt*16 + lg4*4 + e) * 256];
                s[jt][e] = (b > 1e29f) ? -1e-9f : fmaf(s[jt][e], inv_scale, b);
            }

        float m = -INFINITY;
        #pragma unroll
        for (int jt = 0; jt < 16; ++jt) {
            const float a = fmaxf(fmaxf(s[jt][0], s[jt][1]),
                                  fmaxf(s[jt][2], s[jt][3]));
            m = fmaxf(m, a);
        }
        m = fmaxf(m, __shfl_xor(m, 16));
        m = fmaxf(m, __shfl_xor(m, 32));

        float lsum = 0.f;
        #pragma unroll
        for (int jt = 0; jt < 16; ++jt)
            #pragma unroll
            for (int e = 0; e < 4; ++e) {
                const float p = __expf(s[jt][e] - m);
                s[jt][e] = p;
                lsum += p;
            }
        lsum += __shfl_xor(lsum, 16);
        lsum += __shfl_xor(lsum, 32);

        short4v pa[16];
        #pragma unroll
        for (int jt = 0; jt < 16; ++jt) {
            short4v t4;
            t4[0] = f2bf(s[jt][0]); t4[1] = f2bf(s[jt][1]);
            t4[2] = f2bf(s[jt][2]); t4[3] = f2bf(s[jt][3]);
            pa[jt] = t4;
        }

        f32x4 o0 = {0.f,0.f,0.f,0.f}, o1 = {0.f,0.f,0.f,0.f};
        #pragma unroll
        for (int jt = 0; jt < 16; ++jt) {
            o0 = __builtin_amdgcn_mfma_f32_16x16x16bf16_1k(pa[jt], vfrag[jt][0], o0, 0, 0, 0);
            o1 = __builtin_amdgcn_mfma_f32_16x16x16bf16_1k(pa[jt], vfrag[jt][1], o1, 0, 0, 0);
        }

        const float invl = 1.f / lsum;
        float il[4];
        #pragma unroll
        for (int e = 0; e < 4; ++e) il[e] = __shfl(invl, lg4*4 + e);

        __hip_bfloat16* op = attb + ((size_t)(r*256 + it*16) * 128) + h*32;
        #pragma unroll
        for (int e = 0; e < 4; ++e) {
            op[(lg4*4 + e)*128 +      l15] = __float2bfloat16(o0[e] * il[e]);
            op[(lg4*4 + e)*128 + 16 + l15] = __float2bfloat16(o1[e] * il[e]);
        }
    }
}

// =====================================================================
// K3: out = (gate*att) @ w_out + b_out via MFMA. Same skeleton as K1.
// 512 blocks x 256 thr; wave owns 32 tokens.
// =====================================================================
__global__ __launch_bounds__(256) void k3_out_proj(
    const __hip_bfloat16* __restrict__ gateb, const __hip_bfloat16* __restrict__ attb,
    const __hip_bfloat16* __restrict__ woT, const float* __restrict__ b_out,
    float* __restrict__ out)
{
    const int tid = threadIdx.x;
    const int lane = tid & 63, wv = tid >> 6;
    const int l15 = lane & 15, lg4 = lane >> 4;
    const int tokbase = blockIdx.x * 128 + wv * 32;

    const ushort* gu = (const ushort*)gateb;
    const ushort* au = (const ushort*)attb;

    // A = gate*att in bf16 A-frag layout
    short8v afr[2][4];
    #pragma unroll
    for (int mt = 0; mt < 2; ++mt)
        #pragma unroll
        for (int ks = 0; ks < 4; ++ks) {
            const size_t base = (size_t)(tokbase + mt*16 + l15)*128 + ks*32 + lg4*8;
            short8v gv = *(const short8v*)(gu + base);
            short8v av = *(const short8v*)(au + base);
            short8v p;
            #pragma unroll
            for (int e = 0; e < 8; ++e) p[e] = f2bf(bf2f(gv[e]) * bf2f(av[e]));
            afr[mt][ks] = p;
        }

    const ushort* wo = (const ushort*)woT;
    for (int ch = 0; ch < 2; ++ch) {
        f32x4 acc[2][4];
        #pragma unroll
        for (int mt = 0; mt < 2; ++mt)
            #pragma unroll
            for (int nt = 0; nt < 4; ++nt) acc[mt][nt] = (f32x4){0.f,0.f,0.f,0.f};
        const ushort* Bb = wo + (size_t)ch * 64 * 128;
        #pragma unroll
        for (int ks = 0; ks < 4; ++ks)
            #pragma unroll
            for (int nt = 0; nt < 4; ++nt) {
                short8v bfr = *(const short8v*)(Bb + (nt*16 + l15)*128 + ks*32 + lg4*8);
                acc[0][nt] = __builtin_amdgcn_mfma_f32_16x16x32_bf16(afr[0][ks], bfr, acc[0][nt], 0,0,0);
                acc[1][nt] = __builtin_amdgcn_mfma_f32_16x16x32_bf16(afr[1][ks], bfr, acc[1][nt], 0,0,0);
            }
        #pragma unroll
        for (int mt = 0; mt < 2; ++mt)
            #pragma unroll
            for (int nt = 0; nt < 4; ++nt) {
                const int n = ch*64 + nt*16 + l15;
                const float bo = b_out[n];
                #pragma unroll
                for (int e = 0; e < 4; ++e) {
                    const int t = tokbase + mt*16 + lg4*4 + e;
                    out[(size_t)t*128 + n] = acc[mt][nt][e] + bo;
                }
            }
    }
}

extern "C" void kernel_launch(void* const* d_in, const int* in_sizes, int n_in,
                              void* d_out, int out_size, void* d_ws, size_t ws_size,
                              hipStream_t stream)
{
    const float* z       = (const float*)d_in[0];
    const float* gamma   = (const float*)d_in[1];
    const float* beta    = (const float*)d_in[2];
    const float* w_qkv   = (const float*)d_in[3];
    const float* w_pair  = (const float*)d_in[4];
    const float* w_gate  = (const float*)d_in[5];
    const float* b_gate  = (const float*)d_in[6];
    const float* w_out   = (const float*)d_in[7];
    const float* b_out   = (const float*)d_in[8];
    const int*   src_mask= (const int*)d_in[9];
    float* out = (float*)d_out;
    char*  wsb = (char*)d_ws;

    __hip_bfloat16* qb    = (__hip_bfloat16*)(wsb + QB_OFF);
    __hip_bfloat16* kb    = (__hip_bfloat16*)(wsb + KB_OFF);
    __hip_bfloat16* vb    = (__hip_bfloat16*)(wsb + VB_OFF);
    float*          biasf = (float*)(wsb + BIAS_OFF);
    __hip_bfloat16* gateb = (__hip_bfloat16*)(wsb + GATEB_OFF);
    __hip_bfloat16* attb  = (__hip_bfloat16*)(wsb + ATTB_OFF);
    __hip_bfloat16* wT    = (__hip_bfloat16*)(wsb + WT_OFF);
    __hip_bfloat16* woT   = (__hip_bfloat16*)(wsb + WOT_OFF);

    hipLaunchKernelGGL(k_prep_w, dim3(640), dim3(128), 0, stream,
                       w_qkv, w_gate, w_out, wT, woT);
    hipLaunchKernelGGL(k1_ln_proj, dim3(512), dim3(256), 0, stream,
                       z, gamma, beta, w_pair, b_gate, src_mask, wT,
                       qb, kb, vb, biasf, gateb);
    hipLaunchKernelGGL(k_attn_mfma, dim3(1024), dim3(128), 0, stream,
                       qb, kb, vb, biasf, attb);
    hipLaunchKernelGGL(k3_out_proj, dim3(512), dim3(256), 0, stream,
                       gateb, attb, woT, b_out, out);
}